// Round 1
// baseline (14358.575 us; speedup 1.0000x reference)
//
#include <hip/hip_runtime.h>

// Binary-weight 3x3 conv, pad=1 with PAD_VALUE=-1.0, stride 1.
// x: [32,256,56,56] f32, weight: [256,256,3,3] f32 (binarized to +-1 on the fly)
// out: [32,256,56,56] f32
//
// Round 1: correct f32 direct conv baseline.
// Block (16,8): fixed (n,co); thread (tx,ty) computes 4 outputs along w
// (w0=4*tx, tx<14 active) at row h = blockIdx.y*8 + ty.
// Per ci: 3 rows x 6 cols of x (float4 + 2 edge scalars), 36 FMAs with
// wave-uniform (scalar) binarized weights.

#define N_ 32
#define C_ 256
#define H_ 56
#define W_ 56

__global__ __launch_bounds__(128) void bconv_f32_kernel(
    const float* __restrict__ x,
    const float* __restrict__ w,
    float* __restrict__ out)
{
    const int tx = threadIdx.x;            // 0..15, active < 14
    const int ty = threadIdx.y;            // 0..7
    const int nc = blockIdx.x;             // n*256 + co
    const int co = nc & 255;
    const int h  = blockIdx.y * 8 + ty;    // 0..55
    const int w0 = tx * 4;

    if (tx >= 14) return;

    const float* xn = x + (size_t)(nc >> 8) * (C_ * H_ * W_);
    const float* wc = w + (size_t)co * (C_ * 9);

    float acc0 = 0.f, acc1 = 0.f, acc2 = 0.f, acc3 = 0.f;

    const bool rv0 = (h > 0);          // row h-1 valid
    const bool rv2 = (h < H_ - 1);     // row h+1 valid
    const bool cvL = (tx != 0);        // col w0-1 valid
    const bool cvR = (tx != 13);       // col w0+4 valid

    for (int ci = 0; ci < C_; ++ci) {
        const float* xc = xn + ci * (H_ * W_);
        const float* wk = wc + ci * 9;

        float v[3][6];
        #pragma unroll
        for (int r = 0; r < 3; ++r) {
            const bool rv = (r == 0) ? rv0 : (r == 2) ? rv2 : true;
            if (rv) {
                const float* rp = xc + (h + r - 1) * W_;
                const float4 m = *reinterpret_cast<const float4*>(rp + w0);
                v[r][1] = m.x; v[r][2] = m.y; v[r][3] = m.z; v[r][4] = m.w;
                v[r][0] = cvL ? rp[w0 - 1] : -1.0f;
                v[r][5] = cvR ? rp[w0 + 4] : -1.0f;
            } else {
                #pragma unroll
                for (int j = 0; j < 6; ++j) v[r][j] = -1.0f;
            }
        }

        #pragma unroll
        for (int r = 0; r < 3; ++r) {
            #pragma unroll
            for (int c = 0; c < 3; ++c) {
                // weight address is wave-uniform -> s_load; binarize on scalar path
                const float s = (wk[r * 3 + c] >= 0.f) ? 1.0f : -1.0f;
                acc0 = fmaf(s, v[r][c + 0], acc0);
                acc1 = fmaf(s, v[r][c + 1], acc1);
                acc2 = fmaf(s, v[r][c + 2], acc2);
                acc3 = fmaf(s, v[r][c + 3], acc3);
            }
        }
    }

    float* op = out + ((size_t)nc * H_ + h) * W_ + w0;
    *reinterpret_cast<float4*>(op) = make_float4(acc0, acc1, acc2, acc3);
}

extern "C" void kernel_launch(void* const* d_in, const int* in_sizes, int n_in,
                              void* d_out, int out_size, void* d_ws, size_t ws_size,
                              hipStream_t stream) {
    const float* x = (const float*)d_in[0];
    const float* w = (const float*)d_in[1];
    float* out = (float*)d_out;

    dim3 block(16, 8);                 // 128 threads
    dim3 grid(N_ * 256, H_ / 8);       // (8192, 7)
    bconv_f32_kernel<<<grid, block, 0, stream>>>(x, w, out);
}

// Round 2
// 224.042 us; speedup vs baseline: 64.0889x; 64.0889x over previous
//
#include <hip/hip_runtime.h>

// Binary-weight 3x3 conv via implicit GEMM on MFMA (bf16).
// out[co, p] = sum_k wb[co,k] * im2col(x)[k,p],  M=256, N=100352, K=2304.
// Prep: wt[tap][co][ci] binarized bf16; xt[n][58][58][ci] NHWC bf16 with -1 pad.
// GEMM: 128x128 tile, BK=64, 4 waves (2x2), mfma_f32_16x16x32_bf16.

#define N_ 32
#define C_ 256
#define H_ 56
#define W_ 56
#define HP 58
#define SPATIAL (H_ * W_)          // 3136
#define P_TOTAL (N_ * SPATIAL)     // 100352

typedef __attribute__((ext_vector_type(8))) short short8;
typedef __attribute__((ext_vector_type(4))) float f32x4;

__device__ inline unsigned short f2b(float f) {
    unsigned int u = __builtin_bit_cast(unsigned int, f);
    unsigned int r = (u + 0x7FFFu + ((u >> 16) & 1u)) >> 16;
    return (unsigned short)r;
}

// ---------------- prep kernels ----------------

__global__ void fill_xt(unsigned int* p, int n) {
    int i = blockIdx.x * blockDim.x + threadIdx.x;
    int stride = gridDim.x * blockDim.x;
    for (; i < n; i += stride) p[i] = 0xBF80BF80u;   // bf16(-1) x2
}

__global__ void xform_w(const float* __restrict__ w, unsigned short* __restrict__ wt) {
    const int co = blockIdx.x;
    const int ci = threadIdx.x;
    const float* wp = w + ((size_t)co * C_ + ci) * 9;
    #pragma unroll
    for (int tap = 0; tap < 9; ++tap) {
        unsigned short v = (wp[tap] >= 0.f) ? (unsigned short)0x3F80 : (unsigned short)0xBF80;
        wt[((size_t)tap * C_ + co) * C_ + ci] = v;
    }
}

// NCHW f32 -> padded NHWC bf16. Block = one (n, h) row. LDS transpose.
__global__ __launch_bounds__(256) void xform_x(const float* __restrict__ x,
                                               unsigned short* __restrict__ xt) {
    __shared__ unsigned short lds[256][66];   // +2 pad: conflict-free both phases
    const int b = blockIdx.x;                 // n*56 + h
    const int n = b / H_;
    const int h = b - n * H_;
    const int t = threadIdx.x;
    const int wv = t & 63;
    const int wq = t >> 6;

    #pragma unroll 4
    for (int c4 = 0; c4 < 64; ++c4) {
        const int ci = c4 * 4 + wq;
        if (wv < W_)
            lds[ci][wv] = f2b(x[(((size_t)n * C_ + ci) * H_ + h) * W_ + wv]);
    }
    __syncthreads();
    unsigned short* dst = xt + (((size_t)n * HP + h + 1) * HP + 1) * C_ + t;
    for (int ww = 0; ww < W_; ++ww)
        dst[(size_t)ww * C_] = lds[t][ww];
}

// ---------------- main GEMM ----------------
// grid = (784 p-tiles, 2 co-tiles), 256 threads = 4 waves (2x2).

__global__ __launch_bounds__(256) void bgemm(const unsigned short* __restrict__ xt,
                                             const unsigned short* __restrict__ wt,
                                             float* __restrict__ out) {
    const int t = threadIdx.x;
    const int lane = t & 63;
    const int wid = t >> 6;
    const int wr = wid >> 1;      // wave row-block (co)
    const int wc = wid & 1;       // wave col-block (p)
    const int p0 = blockIdx.x * 128;
    const int co0 = blockIdx.y * 128;

    __shared__ unsigned short lds_a[128 * 64];
    __shared__ unsigned short lds_b[128 * 64];

    // staging decomposition: chunk = t + 256*i (i=0..3); row = chunk/8, kc = chunk%8
    const int kc = t & 7;
    const int row_base = t >> 3;  // + 32*i

    // per-thread B source bases (tap/ci added later); positions fixed per block
    int xbase[4];
    #pragma unroll
    for (int i = 0; i < 4; ++i) {
        const int p = p0 + row_base + 32 * i;
        const int n = p / SPATIAL;
        const int r = p - n * SPATIAL;
        const int h = r / W_;
        const int w = r - h * W_;
        xbase[i] = ((n * HP + h) * HP + w) * C_;   // +(kh*58+kw)*256 + ci later
    }

    f32x4 acc[4][4];
    #pragma unroll
    for (int m = 0; m < 4; ++m)
        #pragma unroll
        for (int nn = 0; nn < 4; ++nn)
            acc[m][nn] = (f32x4){0.f, 0.f, 0.f, 0.f};

    for (int tap = 0; tap < 9; ++tap) {
        const int kh = tap / 3;
        const int kw = tap - kh * 3;
        const int xoff = (kh * HP + kw) * C_;
        const unsigned short* wtap = wt + ((size_t)tap * C_ + co0) * C_;

        for (int cb = 0; cb < 4; ++cb) {
            const int ci0 = cb * 64;
            __syncthreads();   // previous compute done before overwrite
            // stage A (weights): lds_a[co_local][ci_local], XOR-swizzled
            #pragma unroll
            for (int i = 0; i < 4; ++i) {
                const int row = row_base + 32 * i;
                const short8 v = *reinterpret_cast<const short8*>(
                    wtap + (size_t)row * C_ + ci0 + kc * 8);
                const int byte = row * 128 + ((kc * 16) ^ ((row & 7) << 4));
                *reinterpret_cast<short8*>((char*)lds_a + byte) = v;
            }
            // stage B (im2col x): lds_b[p_local][ci_local], same swizzle
            #pragma unroll
            for (int i = 0; i < 4; ++i) {
                const int row = row_base + 32 * i;
                const short8 v = *reinterpret_cast<const short8*>(
                    xt + xbase[i] + xoff + ci0 + kc * 8);
                const int byte = row * 128 + ((kc * 16) ^ ((row & 7) << 4));
                *reinterpret_cast<short8*>((char*)lds_b + byte) = v;
            }
            __syncthreads();
            // compute: 2 K=32 halves, 4x4 fragments per wave
            #pragma unroll
            for (int kk = 0; kk < 2; ++kk) {
                const int kb = kk * 64 + ((lane >> 4) * 16);   // byte offset of k-run
                short8 af[4], bf[4];
                #pragma unroll
                for (int m = 0; m < 4; ++m) {
                    const int row = wr * 64 + m * 16 + (lane & 15);
                    const int byte = row * 128 + (kb ^ ((row & 7) << 4));
                    af[m] = *reinterpret_cast<const short8*>((const char*)lds_a + byte);
                }
                #pragma unroll
                for (int nn = 0; nn < 4; ++nn) {
                    const int row = wc * 64 + nn * 16 + (lane & 15);
                    const int byte = row * 128 + (kb ^ ((row & 7) << 4));
                    bf[nn] = *reinterpret_cast<const short8*>((const char*)lds_b + byte);
                }
                #pragma unroll
                for (int m = 0; m < 4; ++m)
                    #pragma unroll
                    for (int nn = 0; nn < 4; ++nn)
                        acc[m][nn] = __builtin_amdgcn_mfma_f32_16x16x32_bf16(
                            af[m], bf[nn], acc[m][nn], 0, 0, 0);
            }
        }
    }

    // epilogue: D[row][col]: col = lane&15 (p), row = (lane>>4)*4 + j (co)
    #pragma unroll
    for (int nn = 0; nn < 4; ++nn) {
        const int p = p0 + wc * 64 + nn * 16 + (lane & 15);
        const int n = p / SPATIAL;
        const int r = p - n * SPATIAL;
        const int h = r / W_;
        const int w = r - h * W_;
        const size_t base = ((size_t)n * C_ + co0 + wr * 64) * SPATIAL + h * W_ + w;
        #pragma unroll
        for (int m = 0; m < 4; ++m) {
            #pragma unroll
            for (int j = 0; j < 4; ++j)
                out[base + (size_t)(m * 16 + (lane >> 4) * 4 + j) * SPATIAL] = acc[m][nn][j];
        }
    }
}

// ---------------- fallback (round-1 f32 direct conv) ----------------

__global__ __launch_bounds__(128) void bconv_f32_kernel(
    const float* __restrict__ x,
    const float* __restrict__ w,
    float* __restrict__ out)
{
    const int tx = threadIdx.x;
    const int ty = threadIdx.y;
    const int nc = blockIdx.x;
    const int co = nc & 255;
    const int h  = blockIdx.y * 8 + ty;
    const int w0 = tx * 4;
    if (tx >= 14) return;

    const float* xn = x + (size_t)(nc >> 8) * (C_ * H_ * W_);
    const float* wc = w + (size_t)co * (C_ * 9);
    float acc0 = 0.f, acc1 = 0.f, acc2 = 0.f, acc3 = 0.f;
    const bool rv0 = (h > 0), rv2 = (h < H_ - 1);
    const bool cvL = (tx != 0), cvR = (tx != 13);

    for (int ci = 0; ci < C_; ++ci) {
        const float* xc = xn + ci * (H_ * W_);
        const float* wk = wc + ci * 9;
        float v[3][6];
        #pragma unroll
        for (int r = 0; r < 3; ++r) {
            const bool rv = (r == 0) ? rv0 : (r == 2) ? rv2 : true;
            if (rv) {
                const float* rp = xc + (h + r - 1) * W_;
                const float4 m = *reinterpret_cast<const float4*>(rp + w0);
                v[r][1] = m.x; v[r][2] = m.y; v[r][3] = m.z; v[r][4] = m.w;
                v[r][0] = cvL ? rp[w0 - 1] : -1.0f;
                v[r][5] = cvR ? rp[w0 + 4] : -1.0f;
            } else {
                #pragma unroll
                for (int j = 0; j < 6; ++j) v[r][j] = -1.0f;
            }
        }
        #pragma unroll
        for (int r = 0; r < 3; ++r)
            #pragma unroll
            for (int c = 0; c < 3; ++c) {
                const float s = (wk[r * 3 + c] >= 0.f) ? 1.0f : -1.0f;
                acc0 = fmaf(s, v[r][c + 0], acc0);
                acc1 = fmaf(s, v[r][c + 1], acc1);
                acc2 = fmaf(s, v[r][c + 2], acc2);
                acc3 = fmaf(s, v[r][c + 3], acc3);
            }
    }
    float* op = out + ((size_t)nc * H_ + h) * W_ + w0;
    *reinterpret_cast<float4*>(op) = make_float4(acc0, acc1, acc2, acc3);
}

// ---------------- launch ----------------

extern "C" void kernel_launch(void* const* d_in, const int* in_sizes, int n_in,
                              void* d_out, int out_size, void* d_ws, size_t ws_size,
                              hipStream_t stream) {
    const float* x = (const float*)d_in[0];
    const float* w = (const float*)d_in[1];
    float* out = (float*)d_out;

    const size_t XT_OFF = 2u * 1024u * 1024u;                     // wt region
    const size_t XT_BYTES = (size_t)N_ * HP * HP * C_ * 2;        // 55,115,776
    const size_t NEEDED = XT_OFF + XT_BYTES;

    if (ws_size >= NEEDED) {
        unsigned short* wt = (unsigned short*)d_ws;
        unsigned short* xt = (unsigned short*)((char*)d_ws + XT_OFF);
        fill_xt<<<4096, 256, 0, stream>>>((unsigned int*)xt, (int)(XT_BYTES / 4));
        xform_w<<<256, 256, 0, stream>>>(w, wt);
        xform_x<<<N_ * H_, 256, 0, stream>>>(x, xt);
        bgemm<<<dim3(P_TOTAL / 128, 2), 256, 0, stream>>>(xt, wt, out);
    } else {
        dim3 block(16, 8);
        dim3 grid(N_ * 256, H_ / 8);
        bconv_f32_kernel<<<grid, block, 0, stream>>>(x, w, out);
    }
}

// Round 3
// 199.995 us; speedup vs baseline: 71.7947x; 1.1202x over previous
//
#include <hip/hip_runtime.h>

// Binary-weight 3x3 conv via implicit GEMM on MFMA (bf16).
// out[co, p] = sum_k wb[co,k] * im2col(x)[k,p],  M=256, N=100352, K=2304.
// Round 3: global_load_lds (width 16) staging with inverse-swizzled source +
// swizzled ds_read (linear LDS dest), grid swapped for B-tile L2 locality,
// fill_xt folded into xform_x.

#define N_ 32
#define C_ 256
#define H_ 56
#define W_ 56
#define HP 58
#define SPATIAL (H_ * W_)          // 3136
#define P_TOTAL (N_ * SPATIAL)     // 100352

typedef __attribute__((ext_vector_type(8))) short short8;
typedef __attribute__((ext_vector_type(4))) float f32x4;

#define GLOAD_LDS16(g, l) __builtin_amdgcn_global_load_lds(                 \
    (const __attribute__((address_space(1))) void*)(g),                     \
    (__attribute__((address_space(3))) void*)(l), 16, 0, 0)

__device__ inline unsigned short f2b(float f) {
    unsigned int u = __builtin_bit_cast(unsigned int, f);
    unsigned int r = (u + 0x7FFFu + ((u >> 16) & 1u)) >> 16;
    return (unsigned short)r;
}

// ---------------- prep kernels ----------------

__global__ void xform_w(const float* __restrict__ w, unsigned short* __restrict__ wt) {
    const int co = blockIdx.x;
    const int ci = threadIdx.x;
    const float* wp = w + ((size_t)co * C_ + ci) * 9;
    #pragma unroll
    for (int tap = 0; tap < 9; ++tap) {
        unsigned short v = (wp[tap] >= 0.f) ? (unsigned short)0x3F80 : (unsigned short)0xBF80;
        wt[((size_t)tap * C_ + co) * C_ + ci] = v;
    }
}

// NCHW f32 -> padded NHWC bf16 (pad value -1). Block = one (n, h) row.
// Also writes this row's pad columns; h==0 blocks write pad rows 0 and 57.
__global__ __launch_bounds__(256) void xform_x(const float* __restrict__ x,
                                               unsigned short* __restrict__ xt) {
    __shared__ unsigned short lds[256][66];   // +2 pad: conflict-free both phases
    const int b = blockIdx.x;                 // n*56 + h
    const int n = b / H_;
    const int h = b - n * H_;
    const int t = threadIdx.x;
    const int wv = t & 63;
    const int wq = t >> 6;

    #pragma unroll 4
    for (int c4 = 0; c4 < 64; ++c4) {
        const int ci = c4 * 4 + wq;
        if (wv < W_)
            lds[ci][wv] = f2b(x[(((size_t)n * C_ + ci) * H_ + h) * W_ + wv]);
    }
    __syncthreads();
    unsigned short* rowp = xt + (((size_t)n * HP + h + 1) * HP) * C_;
    // interior: w = 1..56
    unsigned short* dst = rowp + C_ + t;
    for (int ww = 0; ww < W_; ++ww)
        dst[(size_t)ww * C_] = lds[t][ww];
    // pad columns of this row
    rowp[t] = (unsigned short)0xBF80;                       // w = 0
    rowp[(size_t)57 * C_ + t] = (unsigned short)0xBF80;     // w = 57
    // pad rows (top/bottom) once per n
    if (h == 0) {
        unsigned short* r0  = xt + ((size_t)n * HP) * HP * C_;
        unsigned short* r57 = xt + (((size_t)n * HP + 57) * HP) * C_;
        for (int ww = 0; ww < HP; ++ww) {
            r0 [(size_t)ww * C_ + t] = (unsigned short)0xBF80;
            r57[(size_t)ww * C_ + t] = (unsigned short)0xBF80;
        }
    }
}

// ---------------- main GEMM ----------------
// grid = (2 co-tiles, 784 p-tiles), 256 threads = 4 waves (2x2).
// LDS slot (row, chunk c) holds global chunk c^(row&7); reads XOR (row&7)<<4.

__global__ __launch_bounds__(256) void bgemm(const unsigned short* __restrict__ xt,
                                             const unsigned short* __restrict__ wt,
                                             float* __restrict__ out) {
    const int t = threadIdx.x;
    const int lane = t & 63;
    const int wid = t >> 6;
    const int wr = wid >> 1;      // wave row-block (co)
    const int wc = wid & 1;       // wave col-block (p)
    const int co0 = blockIdx.x * 128;
    const int p0 = blockIdx.y * 128;

    __shared__ unsigned short lds_a[128 * 64];
    __shared__ unsigned short lds_b[128 * 64];

    // staging decomposition: chunk ch = i*256 + t; row = ch>>3, kc = t&7
    const int kc = t & 7;
    const int rb = t >> 3;                    // + 32*i
    const int lds_base = (t & ~63) * 16;      // + i*4096 (wave-uniform)

    int xbase[4];
    #pragma unroll
    for (int i = 0; i < 4; ++i) {
        const int p = p0 + rb + 32 * i;
        const int n = p / SPATIAL;
        const int r = p - n * SPATIAL;
        const int h = r / W_;
        const int w = r - h * W_;
        xbase[i] = ((n * HP + h) * HP + w) * C_;   // +(kh*58+kw)*256 + ci later
    }

    f32x4 acc[4][4];
    #pragma unroll
    for (int m = 0; m < 4; ++m)
        #pragma unroll
        for (int nn = 0; nn < 4; ++nn)
            acc[m][nn] = (f32x4){0.f, 0.f, 0.f, 0.f};

    for (int tap = 0; tap < 9; ++tap) {
        const int kh = tap / 3;
        const int kw = tap - kh * 3;
        const int xoff = (kh * HP + kw) * C_;
        const unsigned short* wtap = wt + ((size_t)tap * C_ + co0) * C_;

        for (int cb = 0; cb < 4; ++cb) {
            const int ci0 = cb * 64;
            __syncthreads();   // previous compute done before overwrite
            #pragma unroll
            for (int i = 0; i < 4; ++i) {
                const int row = rb + 32 * i;
                const int sc = (kc ^ (row & 7)) * 8;           // inverse-swizzled source
                GLOAD_LDS16(wtap + (size_t)row * C_ + ci0 + sc,
                            (char*)lds_a + lds_base + i * 4096);
            }
            #pragma unroll
            for (int i = 0; i < 4; ++i) {
                const int row = rb + 32 * i;
                const int sc = (kc ^ (row & 7)) * 8;
                GLOAD_LDS16(xt + xbase[i] + xoff + ci0 + sc,
                            (char*)lds_b + lds_base + i * 4096);
            }
            __syncthreads();   // drains vmcnt(0): tiles resident
            #pragma unroll
            for (int kk = 0; kk < 2; ++kk) {
                const int kb = kk * 64 + ((lane >> 4) * 16);   // logical k-run byte
                short8 af[4], bf[4];
                #pragma unroll
                for (int m = 0; m < 4; ++m) {
                    const int row = wr * 64 + m * 16 + (lane & 15);
                    const int byte = row * 128 + (kb ^ ((row & 7) << 4));
                    af[m] = *reinterpret_cast<const short8*>((const char*)lds_a + byte);
                }
                #pragma unroll
                for (int nn = 0; nn < 4; ++nn) {
                    const int row = wc * 64 + nn * 16 + (lane & 15);
                    const int byte = row * 128 + (kb ^ ((row & 7) << 4));
                    bf[nn] = *reinterpret_cast<const short8*>((const char*)lds_b + byte);
                }
                #pragma unroll
                for (int m = 0; m < 4; ++m)
                    #pragma unroll
                    for (int nn = 0; nn < 4; ++nn)
                        acc[m][nn] = __builtin_amdgcn_mfma_f32_16x16x32_bf16(
                            af[m], bf[nn], acc[m][nn], 0, 0, 0);
            }
        }
    }

    // epilogue: D[row][col]: col = lane&15 (p), row = (lane>>4)*4 + j (co)
    #pragma unroll
    for (int nn = 0; nn < 4; ++nn) {
        const int p = p0 + wc * 64 + nn * 16 + (lane & 15);
        const int n = p / SPATIAL;
        const int r = p - n * SPATIAL;
        const int h = r / W_;
        const int w = r - h * W_;
        const size_t base = ((size_t)n * C_ + co0 + wr * 64) * SPATIAL + h * W_ + w;
        #pragma unroll
        for (int m = 0; m < 4; ++m) {
            #pragma unroll
            for (int j = 0; j < 4; ++j)
                out[base + (size_t)(m * 16 + (lane >> 4) * 4 + j) * SPATIAL] = acc[m][nn][j];
        }
    }
}

// ---------------- fallback (round-1 f32 direct conv) ----------------

__global__ __launch_bounds__(128) void bconv_f32_kernel(
    const float* __restrict__ x,
    const float* __restrict__ w,
    float* __restrict__ out)
{
    const int tx = threadIdx.x;
    const int ty = threadIdx.y;
    const int nc = blockIdx.x;
    const int co = nc & 255;
    const int h  = blockIdx.y * 8 + ty;
    const int w0 = tx * 4;
    if (tx >= 14) return;

    const float* xn = x + (size_t)(nc >> 8) * (C_ * H_ * W_);
    const float* wc = w + (size_t)co * (C_ * 9);
    float acc0 = 0.f, acc1 = 0.f, acc2 = 0.f, acc3 = 0.f;
    const bool rv0 = (h > 0), rv2 = (h < H_ - 1);
    const bool cvL = (tx != 0), cvR = (tx != 13);

    for (int ci = 0; ci < C_; ++ci) {
        const float* xc = xn + ci * (H_ * W_);
        const float* wk = wc + ci * 9;
        float v[3][6];
        #pragma unroll
        for (int r = 0; r < 3; ++r) {
            const bool rv = (r == 0) ? rv0 : (r == 2) ? rv2 : true;
            if (rv) {
                const float* rp = xc + (h + r - 1) * W_;
                const float4 m = *reinterpret_cast<const float4*>(rp + w0);
                v[r][1] = m.x; v[r][2] = m.y; v[r][3] = m.z; v[r][4] = m.w;
                v[r][0] = cvL ? rp[w0 - 1] : -1.0f;
                v[r][5] = cvR ? rp[w0 + 4] : -1.0f;
            } else {
                #pragma unroll
                for (int j = 0; j < 6; ++j) v[r][j] = -1.0f;
            }
        }
        #pragma unroll
        for (int r = 0; r < 3; ++r)
            #pragma unroll
            for (int c = 0; c < 3; ++c) {
                const float s = (wk[r * 3 + c] >= 0.f) ? 1.0f : -1.0f;
                acc0 = fmaf(s, v[r][c + 0], acc0);
                acc1 = fmaf(s, v[r][c + 1], acc1);
                acc2 = fmaf(s, v[r][c + 2], acc2);
                acc3 = fmaf(s, v[r][c + 3], acc3);
            }
    }
    float* op = out + ((size_t)nc * H_ + h) * W_ + w0;
    *reinterpret_cast<float4*>(op) = make_float4(acc0, acc1, acc2, acc3);
}

// ---------------- launch ----------------

extern "C" void kernel_launch(void* const* d_in, const int* in_sizes, int n_in,
                              void* d_out, int out_size, void* d_ws, size_t ws_size,
                              hipStream_t stream) {
    const float* x = (const float*)d_in[0];
    const float* w = (const float*)d_in[1];
    float* out = (float*)d_out;

    const size_t XT_OFF = 2u * 1024u * 1024u;                     // wt region
    const size_t XT_BYTES = (size_t)N_ * HP * HP * C_ * 2;        // 55,115,776
    const size_t NEEDED = XT_OFF + XT_BYTES;

    if (ws_size >= NEEDED) {
        unsigned short* wt = (unsigned short*)d_ws;
        unsigned short* xt = (unsigned short*)((char*)d_ws + XT_OFF);
        xform_w<<<256, 256, 0, stream>>>(w, wt);
        xform_x<<<N_ * H_, 256, 0, stream>>>(x, xt);
        bgemm<<<dim3(2, P_TOTAL / 128), 256, 0, stream>>>(xt, wt, out);
    } else {
        dim3 block(16, 8);
        dim3 grid(N_ * 256, H_ / 8);
        bconv_f32_kernel<<<grid, block, 0, stream>>>(x, w, out);
    }
}

// Round 4
// 158.763 us; speedup vs baseline: 90.4406x; 1.2597x over previous
//
#include <hip/hip_runtime.h>

// Binary-weight 3x3 conv via implicit GEMM on MFMA (bf16).
// out[co, p] = sum_k wb[co,k] * im2col(x)[k,p],  M=256, N=100352, K=2304.
// Round 4: 256x224 tile, BK=64, 8 waves (4 co x 2 p), double-buffered LDS
// (120KB dynamic) with 2-phase prefetch (stage next || compute cur, one
// barrier per K-step), K-loop cb-outer/tap-inner for L2 tap reuse.

#define N_ 32
#define C_ 256
#define H_ 56
#define W_ 56
#define HP 58
#define SPATIAL (H_ * W_)          // 3136
#define P_TOTAL (N_ * SPATIAL)     // 100352
#define BNP 224
#define NBLK (P_TOTAL / BNP)       // 448
#define KSTEPS 36

typedef __attribute__((ext_vector_type(8))) short short8;
typedef __attribute__((ext_vector_type(4))) float f32x4;

#define GLOAD_LDS16(g, l) __builtin_amdgcn_global_load_lds(                 \
    (const __attribute__((address_space(1))) void*)(g),                     \
    (__attribute__((address_space(3))) void*)(l), 16, 0, 0)

__device__ inline unsigned short f2b(float f) {
    unsigned int u = __builtin_bit_cast(unsigned int, f);
    unsigned int r = (u + 0x7FFFu + ((u >> 16) & 1u)) >> 16;
    return (unsigned short)r;
}

// ---------------- prep kernels ----------------

__global__ void xform_w(const float* __restrict__ w, unsigned short* __restrict__ wt) {
    const int co = blockIdx.x;
    const int ci = threadIdx.x;
    const float* wp = w + ((size_t)co * C_ + ci) * 9;
    #pragma unroll
    for (int tap = 0; tap < 9; ++tap) {
        unsigned short v = (wp[tap] >= 0.f) ? (unsigned short)0x3F80 : (unsigned short)0xBF80;
        wt[((size_t)tap * C_ + co) * C_ + ci] = v;
    }
}

// NCHW f32 -> padded NHWC bf16 (pad value -1). Block = one (n, h) row.
__global__ __launch_bounds__(256) void xform_x(const float* __restrict__ x,
                                               unsigned short* __restrict__ xt) {
    __shared__ unsigned short lds[256][66];
    const int b = blockIdx.x;                 // n*56 + h
    const int n = b / H_;
    const int h = b - n * H_;
    const int t = threadIdx.x;
    const int wv = t & 63;
    const int wq = t >> 6;

    #pragma unroll 4
    for (int c4 = 0; c4 < 64; ++c4) {
        const int ci = c4 * 4 + wq;
        if (wv < W_)
            lds[ci][wv] = f2b(x[(((size_t)n * C_ + ci) * H_ + h) * W_ + wv]);
    }
    __syncthreads();
    unsigned short* rowp = xt + (((size_t)n * HP + h + 1) * HP) * C_;
    unsigned short* dst = rowp + C_ + t;
    for (int ww = 0; ww < W_; ++ww)
        dst[(size_t)ww * C_] = lds[t][ww];
    rowp[t] = (unsigned short)0xBF80;                       // w = 0 pad
    rowp[(size_t)57 * C_ + t] = (unsigned short)0xBF80;     // w = 57 pad
    if (h == 0) {
        unsigned short* r0  = xt + ((size_t)n * HP) * HP * C_;
        unsigned short* r57 = xt + (((size_t)n * HP + 57) * HP) * C_;
        for (int ww = 0; ww < HP; ++ww) {
            r0 [(size_t)ww * C_ + t] = (unsigned short)0xBF80;
            r57[(size_t)ww * C_ + t] = (unsigned short)0xBF80;
        }
    }
}

// ---------------- main GEMM ----------------
// grid = 448 blocks (one 224-p tile each, all 256 co), 512 threads = 8 waves.
// Wave (wm 0..3, wn 0..1): 64 co x 112 p = 4x7 16x16 fragments.
// LDS: A dbuf 2x32KB @0, B dbuf 2x28KB @65536. Slot (row,kc) holds source
// chunk kc^(row&7); fragment reads XOR (row&7)<<4 (verified R2/R3 scheme).

__global__ __launch_bounds__(512, 2) void bgemm(const unsigned short* __restrict__ xt,
                                                const unsigned short* __restrict__ wt,
                                                float* __restrict__ out) {
    extern __shared__ char smem[];
    const int t = threadIdx.x;
    const int lane = t & 63;
    const int wm = (t >> 6) >> 1;     // 0..3
    const int wn = (t >> 6) & 1;      // 0..1
    const int blk = blockIdx.x;
    const int n  = blk / 14;
    const int sp0 = (blk % 14) * BNP;
    const int h0 = (blk % 14) * 4;

    // staging precompute: chunk c = i*512 + t; row = c>>3; dest byte = c*16
    const int kcs = ((t & 7) ^ ((t >> 3) & 7)) * 8;   // swizzled ci sub-offset (elems)
    int arow[4], xrow[4];
    #pragma unroll
    for (int i = 0; i < 4; ++i) {
        const int r = i * 64 + (t >> 3);
        arow[i] = r * C_ + kcs;
        const int rr = (r < BNP) ? r : 0;             // i==3,t>=256 unused
        xrow[i] = ((n * HP + h0 + rr / W_) * HP + (rr % W_)) * C_ + kcs;
    }
    const int dstc = t * 16;

    // fragment-read precompute
    const int xorv = (lane & 7) << 4;
    int aRB[4], bRB[7];
    #pragma unroll
    for (int m = 0; m < 4; ++m) aRB[m] = (wm * 64 + m * 16 + (lane & 15)) * 128;
    #pragma unroll
    for (int nn = 0; nn < 7; ++nn) bRB[nn] = (wn * 112 + nn * 16 + (lane & 15)) * 128;

    f32x4 acc[4][7];
    #pragma unroll
    for (int m = 0; m < 4; ++m)
        #pragma unroll
        for (int nn = 0; nn < 7; ++nn)
            acc[m][nn] = (f32x4){0.f, 0.f, 0.f, 0.f};

    // K-step s: cb = s/9 (ci block), tap = s%9  (tap fastest -> L2 tap reuse)
    auto stage = [&](int s, int buf) {
        const int cb = s / 9;
        const int tap = s - cb * 9;
        const int kh = tap / 3, kw = tap - kh * 3;
        const unsigned short* asrc = wt + tap * (C_ * C_) + cb * 64;
        const unsigned short* bsrc = xt + (kh * HP + kw) * C_ + cb * 64;
        char* la = smem + buf * 32768;
        char* lb = smem + 65536 + buf * 28672;
        #pragma unroll
        for (int i = 0; i < 4; ++i)
            GLOAD_LDS16(asrc + arow[i], la + i * 8192 + dstc);
        #pragma unroll
        for (int i = 0; i < 3; ++i)
            GLOAD_LDS16(bsrc + xrow[i], lb + i * 8192 + dstc);
        if (t < 256)                                   // wave-uniform guard
            GLOAD_LDS16(bsrc + xrow[3], lb + 3 * 8192 + dstc);
    };

    auto compute = [&](int buf) {
        const char* Ab = smem + buf * 32768;
        const char* Bb = smem + 65536 + buf * 28672;
        #pragma unroll
        for (int kq = 0; kq < 2; ++kq) {
            const int kb = kq * 64 + ((lane >> 4) * 16);
            short8 af[4], bf[7];
            #pragma unroll
            for (int m = 0; m < 4; ++m)
                af[m] = *reinterpret_cast<const short8*>(Ab + aRB[m] + (kb ^ xorv));
            #pragma unroll
            for (int nn = 0; nn < 7; ++nn)
                bf[nn] = *reinterpret_cast<const short8*>(Bb + bRB[nn] + (kb ^ xorv));
            __builtin_amdgcn_s_setprio(1);
            #pragma unroll
            for (int m = 0; m < 4; ++m)
                #pragma unroll
                for (int nn = 0; nn < 7; ++nn)
                    acc[m][nn] = __builtin_amdgcn_mfma_f32_16x16x32_bf16(
                        af[m], bf[nn], acc[m][nn], 0, 0, 0);
            __builtin_amdgcn_s_setprio(0);
        }
    };

    stage(0, 0);
    __syncthreads();
    for (int s = 0; s < KSTEPS; s += 2) {
        stage(s + 1, 1);                  // s+1 <= 35 always
        compute(0);
        __syncthreads();
        if (s + 2 < KSTEPS) stage(s + 2, 0);
        compute(1);
        if (s + 2 < KSTEPS) __syncthreads();
    }

    // epilogue: frag D col = lane&15 (p), row = (lane>>4)*4 + j (co).
    // 224-p tile is spatially contiguous within image n.
    #pragma unroll
    for (int m = 0; m < 4; ++m) {
        #pragma unroll
        for (int j = 0; j < 4; ++j) {
            const int co = wm * 64 + m * 16 + (lane >> 4) * 4 + j;
            float* op = out + (size_t)(n * C_ + co) * SPATIAL + sp0 + wn * 112 + (lane & 15);
            #pragma unroll
            for (int nn = 0; nn < 7; ++nn)
                op[nn * 16] = acc[m][nn][j];
        }
    }
}

// ---------------- fallback (round-1 f32 direct conv) ----------------

__global__ __launch_bounds__(128) void bconv_f32_kernel(
    const float* __restrict__ x,
    const float* __restrict__ w,
    float* __restrict__ out)
{
    const int tx = threadIdx.x;
    const int ty = threadIdx.y;
    const int nc = blockIdx.x;
    const int co = nc & 255;
    const int h  = blockIdx.y * 8 + ty;
    const int w0 = tx * 4;
    if (tx >= 14) return;

    const float* xn = x + (size_t)(nc >> 8) * (C_ * H_ * W_);
    const float* wc = w + (size_t)co * (C_ * 9);
    float acc0 = 0.f, acc1 = 0.f, acc2 = 0.f, acc3 = 0.f;
    const bool rv0 = (h > 0), rv2 = (h < H_ - 1);
    const bool cvL = (tx != 0), cvR = (tx != 13);

    for (int ci = 0; ci < C_; ++ci) {
        const float* xc = xn + ci * (H_ * W_);
        const float* wk = wc + ci * 9;
        float v[3][6];
        #pragma unroll
        for (int r = 0; r < 3; ++r) {
            const bool rv = (r == 0) ? rv0 : (r == 2) ? rv2 : true;
            if (rv) {
                const float* rp = xc + (h + r - 1) * W_;
                const float4 m = *reinterpret_cast<const float4*>(rp + w0);
                v[r][1] = m.x; v[r][2] = m.y; v[r][3] = m.z; v[r][4] = m.w;
                v[r][0] = cvL ? rp[w0 - 1] : -1.0f;
                v[r][5] = cvR ? rp[w0 + 4] : -1.0f;
            } else {
                #pragma unroll
                for (int j = 0; j < 6; ++j) v[r][j] = -1.0f;
            }
        }
        #pragma unroll
        for (int r = 0; r < 3; ++r)
            #pragma unroll
            for (int c = 0; c < 3; ++c) {
                const float s = (wk[r * 3 + c] >= 0.f) ? 1.0f : -1.0f;
                acc0 = fmaf(s, v[r][c + 0], acc0);
                acc1 = fmaf(s, v[r][c + 1], acc1);
                acc2 = fmaf(s, v[r][c + 2], acc2);
                acc3 = fmaf(s, v[r][c + 3], acc3);
            }
    }
    float* op = out + ((size_t)nc * H_ + h) * W_ + w0;
    *reinterpret_cast<float4*>(op) = make_float4(acc0, acc1, acc2, acc3);
}

// ---------------- launch ----------------

extern "C" void kernel_launch(void* const* d_in, const int* in_sizes, int n_in,
                              void* d_out, int out_size, void* d_ws, size_t ws_size,
                              hipStream_t stream) {
    const float* x = (const float*)d_in[0];
    const float* w = (const float*)d_in[1];
    float* out = (float*)d_out;

    const size_t XT_OFF = 2u * 1024u * 1024u;
    const size_t XT_BYTES = (size_t)N_ * HP * HP * C_ * 2;
    const size_t NEEDED = XT_OFF + XT_BYTES;
    const int LDS_BYTES = 122880;   // A 2x32KB + B 2x28KB

    if (ws_size >= NEEDED) {
        unsigned short* wt = (unsigned short*)d_ws;
        unsigned short* xt = (unsigned short*)((char*)d_ws + XT_OFF);
        hipFuncSetAttribute((const void*)&bgemm,
                            hipFuncAttributeMaxDynamicSharedMemorySize, LDS_BYTES);
        xform_w<<<256, 256, 0, stream>>>(w, wt);
        xform_x<<<N_ * H_, 256, 0, stream>>>(x, xt);
        bgemm<<<NBLK, 512, LDS_BYTES, stream>>>(xt, wt, out);
    } else {
        dim3 block(16, 8);
        dim3 grid(N_ * 256, H_ / 8);
        bconv_f32_kernel<<<grid, block, 0, stream>>>(x, w, out);
    }
}